// Round 3
// baseline (248.098 us; speedup 1.0000x reference)
//
#include <hip/hip_runtime.h>
#include <hip/hip_cooperative_groups.h>

namespace cg = cooperative_groups;

#define DIM 768
#define NB  32
#define LQ  512
#define NV  128

typedef unsigned short u16;
typedef unsigned int   u32;
typedef __bf16 bf16x8 __attribute__((ext_vector_type(8)));
typedef float  f32x4  __attribute__((ext_vector_type(4)));
typedef u16    u16x8  __attribute__((ext_vector_type(8)));
typedef u16    u16x4  __attribute__((ext_vector_type(4)));

typedef __attribute__((address_space(1))) const void gvoid;
typedef __attribute__((address_space(3))) void       svoid;

__device__ __forceinline__ u16 f2bf(float f) {
    u32 u = __float_as_uint(f);
    return (u16)((u + 0x7FFFu + ((u >> 16) & 1u)) >> 16);   // RNE
}

__device__ __forceinline__ bf16x8 ld_frag(const u16* p) {
    return __builtin_bit_cast(bf16x8, *(const u16x8*)p);
}

__device__ __forceinline__ void gld16(const void* g, void* l) {
    __builtin_amdgcn_global_load_lds((gvoid*)g, (svoid*)l, 16, 0, 0);
}

// ===========================================================================
// Fused cooperative kernel: 256 blocks x 512 threads, 2 grid syncs.
//   Phase A: blocks [0,36)   W2 = Wq^T Wk (full-K, direct stores, no atomics)
//            blocks [36,228) videos -> vt2 (PV frag order) + vbf (bf16)
//   Phase B: blocks [0,192)  G = vbf @ W2^T  (bf16, 128x128 tile)
//   Phase C: all 256 blocks  attention (Q from lines fp32, K = G)
// ===========================================================================
__global__ __launch_bounds__(512) void fused_kernel(const float* __restrict__ lines,
                                                    const float* __restrict__ videos,
                                                    const int*   __restrict__ mask,
                                                    const float* __restrict__ w_q,
                                                    const float* __restrict__ w_k,
                                                    float* __restrict__ out,
                                                    u16* __restrict__ gw,
                                                    u16* __restrict__ vt2,
                                                    u16* __restrict__ vbf,
                                                    float* __restrict__ w2f) {
    __shared__ union {
        struct { u16 q[128][72]; u16 k[128][72]; } w2s;        // A: 36 KB
        u16 T[2][64][136];                                     // A: 34.8 KB
        struct { u16 A[128][64]; u16 B[128][72]; } gs;         // B: 34 KB
        struct {
            union {
                struct { u16 q[2][64][64]; u16 k[2][128][64]; } st;  // 48 KB
                float s[64][132];
            } u;
            u16 p[64][136];
            float bias[128];
        } at;                                                  // C: 65.5 KB
    } sm;

    const int bx   = blockIdx.x;
    const int t    = threadIdx.x;
    const int w    = t >> 6;
    const int lane = t & 63;
    const int quad = lane >> 4;
    const int ln   = lane & 15;

    // ================= Phase A =================
    if (bx < 36) {
        // ---- W2[m][n] = sum_e wq[e][m]*wk[e][n], one block per 128x128 tile ----
        const int m0 = (bx / 6) * 128;
        const int n0 = (bx % 6) * 128;
        const int wr = (w >> 1) * 32;                   // 8 waves: 4x2 of 32x64
        const int wc = (w & 1) * 64;
        f32x4 acc[2][4] = {};
        for (int ks = 0; ks < 12; ++ks) {
            __syncthreads();
            const int e0 = ks * 64;
#pragma unroll
            for (int p = 0; p < 4; ++p) {               // 64 e-rows x 32 d-float4
                int f  = t + p * 512;
                int r  = f >> 5;                        // e row [0,64)
                int c4 = f & 31;                        // d chunk [0,32)
                float4 xq = *(const float4*)(w_q + (size_t)(e0 + r) * DIM + m0 + c4 * 4);
                float4 xk = *(const float4*)(w_k + (size_t)(e0 + r) * DIM + n0 + c4 * 4);
                int swz = ((r >> 3) ^ ((c4 >> 1) & 7)) * 8 + (r & 7);
                sm.w2s.q[c4 * 4 + 0][swz] = f2bf(xq.x);
                sm.w2s.q[c4 * 4 + 1][swz] = f2bf(xq.y);
                sm.w2s.q[c4 * 4 + 2][swz] = f2bf(xq.z);
                sm.w2s.q[c4 * 4 + 3][swz] = f2bf(xq.w);
                sm.w2s.k[c4 * 4 + 0][swz] = f2bf(xk.x);
                sm.w2s.k[c4 * 4 + 1][swz] = f2bf(xk.y);
                sm.w2s.k[c4 * 4 + 2][swz] = f2bf(xk.z);
                sm.w2s.k[c4 * 4 + 3][swz] = f2bf(xk.w);
            }
            __syncthreads();
#pragma unroll
            for (int kk = 0; kk < 2; ++kk) {
                bf16x8 af[2], bfr[4];
#pragma unroll
                for (int i = 0; i < 2; ++i) {
                    int row = wr + i * 16 + ln;
                    af[i]  = ld_frag(&sm.w2s.q[row][((kk * 4 + quad) ^ ((row >> 3) & 7)) * 8]);
                }
#pragma unroll
                for (int j = 0; j < 4; ++j) {
                    int row = wc + j * 16 + ln;
                    bfr[j] = ld_frag(&sm.w2s.k[row][((kk * 4 + quad) ^ ((row >> 3) & 7)) * 8]);
                }
#pragma unroll
                for (int i = 0; i < 2; ++i)
#pragma unroll
                    for (int j = 0; j < 4; ++j)
                        acc[i][j] = __builtin_amdgcn_mfma_f32_16x16x32_bf16(af[i], bfr[j], acc[i][j], 0, 0, 0);
            }
        }
#pragma unroll
        for (int i = 0; i < 2; ++i)
#pragma unroll
            for (int j = 0; j < 4; ++j)
#pragma unroll
                for (int r = 0; r < 4; ++r)
                    w2f[(size_t)(m0 + wr + i * 16 + quad * 4 + r) * DIM +
                        n0 + wc + j * 16 + ln] = acc[i][j][r];
    } else if (bx < 36 + 192) {
        // ---- videos -> vt2 + vbf, two 256-thread half-units per block ----
        const int unit0 = (bx - 36) * 2;
        if (unit0 < 384) {
            const int half = t >> 8;
            const int tl   = t & 255;
            const int v    = unit0 + half;              // [0,384)
            const int b    = v / 12;
            const int d0   = (v % 12) * 64;
            const float* src = videos + (size_t)b * NV * DIM;
#pragma unroll
            for (int p = 0; p < 8; ++p) {
                int f  = tl + p * 256;
                int vv = f >> 4;
                int c4 = f & 15;
                float4 x = *(const float4*)(src + (size_t)vv * DIM + d0 + c4 * 4);
                u16x4 o = { f2bf(x.x), f2bf(x.y), f2bf(x.z), f2bf(x.w) };
                sm.T[half][c4 * 4 + 0][vv] = o[0];
                sm.T[half][c4 * 4 + 1][vv] = o[1];
                sm.T[half][c4 * 4 + 2][vv] = o[2];
                sm.T[half][c4 * 4 + 3][vv] = o[3];
                *(u16x4*)(vbf + ((size_t)b * NV + vv) * DIM + d0 + c4 * 4) = o;
            }
            __syncthreads();
#pragma unroll
            for (int p = 0; p < 4; ++p) {
                int f  = tl + p * 256;
                int dl = f >> 4;
                int v8 = f & 15;                        // = ks*4 + quad
                int d  = d0 + dl;
                int it = d >> 7, wv = (d >> 4) & 7, lnn = d & 15;
                int ksv = v8 >> 2, qd = v8 & 3;
                int lane2 = qd * 16 + lnn;
                size_t off = ((((size_t)b * 6 + it) * 8 + wv) * 4 + ksv) * 512 + lane2 * 8;
                *(u16x8*)(vt2 + off) = *(const u16x8*)&sm.T[half][dl][v8 * 8];
            }
        }
    }

    cg::this_grid().sync();

    // ================= Phase B: G = vbf @ W2^T =================
    if (bx < 192) {
        int m0, n0;
        {
            int i = bx;
            int xcd = i & 7, s = i >> 3;
            m0 = ((s / 6) * 8 + xcd) * 128;
            n0 = (s % 6) * 128;
        }
        const int wr = (w >> 2) * 64;
        const int wc = (w & 3) * 32;
        const int srow   = lane >> 3;
        const int schunk = (lane & 7) ^ srow;

        f32x4 acc[4][2] = {};
#pragma unroll
        for (int ks = 0; ks < 12; ++ks) {
            __syncthreads();
#pragma unroll
            for (int p = 0; p < 2; ++p) {               // A: 128 rows via gld16
                int rb = w * 16 + p * 8;
                gld16(vbf + (size_t)(m0 + rb + srow) * DIM + ks * 64 + schunk * 8, &sm.gs.A[rb][0]);
            }
#pragma unroll
            for (int p = 0; p < 4; ++p) {               // B: 128 rows x 64 fp32, convert
                int idx = t + p * 512;
                int row = idx >> 4, c4 = idx & 15;
                float4 x = *(const float4*)(w2f + (size_t)(n0 + row) * DIM + ks * 64 + c4 * 4);
                u16x4 o = { f2bf(x.x), f2bf(x.y), f2bf(x.z), f2bf(x.w) };
                int swz = ((c4 >> 1) ^ (row & 7)) * 8 + (c4 & 1) * 4;
                *(u16x4*)&sm.gs.B[row][swz] = o;
            }
            __syncthreads();
#pragma unroll
            for (int kk = 0; kk < 2; ++kk) {
                bf16x8 af[4], bfr[2];
#pragma unroll
                for (int i = 0; i < 4; ++i)
                    af[i]  = ld_frag(&sm.gs.A[wr + i * 16 + ln][((kk * 4 + quad) ^ (ln & 7)) * 8]);
#pragma unroll
                for (int j = 0; j < 2; ++j)
                    bfr[j] = ld_frag(&sm.gs.B[wc + j * 16 + ln][((kk * 4 + quad) ^ (ln & 7)) * 8]);
#pragma unroll
                for (int i = 0; i < 4; ++i)
#pragma unroll
                    for (int j = 0; j < 2; ++j)
                        acc[i][j] = __builtin_amdgcn_mfma_f32_16x16x32_bf16(af[i], bfr[j], acc[i][j], 0, 0, 0);
            }
        }
#pragma unroll
        for (int i = 0; i < 4; ++i)
#pragma unroll
            for (int j = 0; j < 2; ++j)
#pragma unroll
                for (int r = 0; r < 4; ++r)
                    gw[(size_t)(m0 + wr + i * 16 + quad * 4 + r) * DIM + n0 + wc + j * 16 + ln] =
                        f2bf(acc[i][j][r]);
    }

    cg::this_grid().sync();

    // ================= Phase C: attention =================
    {
        int b, l0;
        {
            int i = bx;
            int xcd = i & 7, s = i >> 3;
            b  = (s >> 3) * 8 + xcd;
            l0 = (s & 7) * 64;
        }
        const float* Qb = lines + ((size_t)b * LQ + l0) * DIM;
        const u16*   Kb = gw + (size_t)b * NV * DIM;
        if (t < NV) sm.at.bias[t] = mask[b * NV + t] ? 0.0f : -1e9f;

        const int srow   = lane >> 3;
        const int schunk = (lane & 7) ^ srow;
        const int qrow = t >> 3;
        const int qc8  = t & 7;
        const int qswz = (qc8 ^ (qrow & 7)) * 8;

        auto stageK = [&](int ks, int sel) {
            gld16(Kb + (size_t)(w * 16 + srow) * DIM + ks * 64 + schunk * 8, &sm.at.u.st.k[sel][w * 16][0]);
            gld16(Kb + (size_t)(w * 16 + 8 + srow) * DIM + ks * 64 + schunk * 8, &sm.at.u.st.k[sel][w * 16 + 8][0]);
        };
        auto loadQ = [&](int ks, float4& x0, float4& x1) {
            const float* p = Qb + (size_t)qrow * DIM + ks * 64 + qc8 * 8;
            x0 = *(const float4*)p;
            x1 = *(const float4*)(p + 4);
        };
        auto writeQ = [&](int sel, const float4& x0, const float4& x1) {
            u16x8 o = { f2bf(x0.x), f2bf(x0.y), f2bf(x0.z), f2bf(x0.w),
                        f2bf(x1.x), f2bf(x1.y), f2bf(x1.z), f2bf(x1.w) };
            *(u16x8*)&sm.at.u.st.q[sel][qrow][qswz] = o;
        };

        // ---- S = Q K^T ----
        f32x4 accS[4] = {};
        {
            float4 x0, x1;
            loadQ(0, x0, x1);
            stageK(0, 0);
            writeQ(0, x0, x1);
        }
#pragma unroll
        for (int ks = 0; ks < 12; ++ks) {
            __syncthreads();
            const int sel = ks & 1;
            float4 nx0, nx1;
            if (ks < 11) {
                loadQ(ks + 1, nx0, nx1);
                stageK(ks + 1, sel ^ 1);
            }
#pragma unroll
            for (int kk = 0; kk < 2; ++kk) {
                bf16x8 bfr = ld_frag(&sm.at.u.st.k[sel][w * 16 + ln][((kk * 4 + quad) ^ (ln & 7)) * 8]);
#pragma unroll
                for (int i = 0; i < 4; ++i) {
                    bf16x8 af = ld_frag(&sm.at.u.st.q[sel][i * 16 + ln][((kk * 4 + quad) ^ (ln & 7)) * 8]);
                    accS[i] = __builtin_amdgcn_mfma_f32_16x16x32_bf16(af, bfr, accS[i], 0, 0, 0);
                }
            }
            if (ks < 11) writeQ(sel ^ 1, nx0, nx1);
        }
        __syncthreads();
        const float scale = 0.03608439182435161f;       // 768^-0.5
#pragma unroll
        for (int i = 0; i < 4; ++i)
#pragma unroll
            for (int r = 0; r < 4; ++r)
                sm.at.u.s[i * 16 + quad * 4 + r][w * 16 + ln] = accS[i][r] * scale;
        __syncthreads();

        // ---- masked softmax ----
        {
            const int row = t >> 3, seg = t & 7;
            float vals[16];
            float mx = -3.0e38f;
#pragma unroll
            for (int c = 0; c < 4; ++c) {
                float4 x  = *(const float4*)&sm.at.u.s[row][seg * 16 + c * 4];
                float4 bz = *(const float4*)&sm.at.bias[seg * 16 + c * 4];
                float a0 = x.x + bz.x, a1 = x.y + bz.y, a2 = x.z + bz.z, a3 = x.w + bz.w;
                vals[c * 4 + 0] = a0; vals[c * 4 + 1] = a1;
                vals[c * 4 + 2] = a2; vals[c * 4 + 3] = a3;
                mx = fmaxf(mx, fmaxf(fmaxf(a0, a1), fmaxf(a2, a3)));
            }
            mx = fmaxf(mx, __shfl_xor(mx, 1));
            mx = fmaxf(mx, __shfl_xor(mx, 2));
            mx = fmaxf(mx, __shfl_xor(mx, 4));
            float sum = 0.0f;
#pragma unroll
            for (int c = 0; c < 16; ++c) { float e = __expf(vals[c] - mx); vals[c] = e; sum += e; }
            sum += __shfl_xor(sum, 1);
            sum += __shfl_xor(sum, 2);
            sum += __shfl_xor(sum, 4);
            const float inv = 1.0f / sum;
#pragma unroll
            for (int h = 0; h < 2; ++h) {
                u16x8 pk;
#pragma unroll
                for (int e = 0; e < 8; ++e) pk[e] = f2bf(vals[h * 8 + e] * inv);
                *(u16x8*)&sm.at.p[row][seg * 16 + h * 8] = pk;
            }
        }
        __syncthreads();

        bf16x8 paf[4][4];
#pragma unroll
        for (int i = 0; i < 4; ++i)
#pragma unroll
            for (int ks = 0; ks < 4; ++ks)
                paf[i][ks] = ld_frag(&sm.at.p[i * 16 + ln][ks * 32 + quad * 8]);

        // ---- out = P @ V ----
        const u16* V2 = vt2 + (size_t)b * 6 * 8 * 4 * 512;
        float*     Ob = out + ((size_t)b * LQ + l0) * DIM;
        for (int it = 0; it < 6; ++it) {
            f32x4 accO[4] = {};
#pragma unroll
            for (int ks = 0; ks < 4; ++ks) {
                bf16x8 bv = ld_frag(V2 + (((size_t)(it * 8 + w)) * 4 + ks) * 512 + lane * 8);
#pragma unroll
                for (int i = 0; i < 4; ++i)
                    accO[i] = __builtin_amdgcn_mfma_f32_16x16x32_bf16(paf[i][ks], bv, accO[i], 0, 0, 0);
            }
#pragma unroll
            for (int i = 0; i < 4; ++i)
#pragma unroll
                for (int r = 0; r < 4; ++r)
                    Ob[(size_t)(i * 16 + quad * 4 + r) * DIM + it * 128 + w * 16 + ln] = accO[i][r];
        }
    }
}

// ===========================================================================
// Fallback path (round-2 proven kernels), used only if cooperative launch
// is rejected at runtime.
// ===========================================================================
#define W2S    4
#define W2_BLK (36 * W2S)

__global__ __launch_bounds__(256) void prep_kernel(const float* __restrict__ w_q,
                                                   const float* __restrict__ w_k,
                                                   const float* __restrict__ videos,
                                                   float* __restrict__ w2f,
                                                   u16* __restrict__ vt2,
                                                   u16* __restrict__ vbf) {
    __shared__ union {
        u16 T[64][136];
        struct { u16 q[128][72]; u16 k[128][72]; } w2s;
    } uL;
    const int bx = blockIdx.x;
    const int t  = threadIdx.x;

    if (bx < W2_BLK) {
        const int tile = bx / W2S, kc = bx % W2S;
        const int m0 = (tile / 6) * 128;
        const int n0 = (tile % 6) * 128;
        const int w    = t >> 6;
        const int lane = t & 63;
        const int quad = lane >> 4;
        const int ln   = lane & 15;
        const int wr   = (w >> 1) * 64;
        const int wc   = (w & 1) * 64;
        f32x4 acc[4][4] = {};
        for (int ks = kc * 3; ks < kc * 3 + 3; ++ks) {
            __syncthreads();
            const int e0 = ks * 64;
#pragma unroll
            for (int p = 0; p < 8; ++p) {
                int f  = t + p * 256;
                int r  = f >> 5;
                int c4 = f & 31;
                float4 xq = *(const float4*)(w_q + (size_t)(e0 + r) * DIM + m0 + c4 * 4);
                float4 xk = *(const float4*)(w_k + (size_t)(e0 + r) * DIM + n0 + c4 * 4);
                int swz = ((r >> 3) ^ ((c4 >> 1) & 7)) * 8 + (r & 7);
                uL.w2s.q[c4 * 4 + 0][swz] = f2bf(xq.x);
                uL.w2s.q[c4 * 4 + 1][swz] = f2bf(xq.y);
                uL.w2s.q[c4 * 4 + 2][swz] = f2bf(xq.z);
                uL.w2s.q[c4 * 4 + 3][swz] = f2bf(xq.w);
                uL.w2s.k[c4 * 4 + 0][swz] = f2bf(xk.x);
                uL.w2s.k[c4 * 4 + 1][swz] = f2bf(xk.y);
                uL.w2s.k[c4 * 4 + 2][swz] = f2bf(xk.z);
                uL.w2s.k[c4 * 4 + 3][swz] = f2bf(xk.w);
            }
            __syncthreads();
#pragma unroll
            for (int kk = 0; kk < 2; ++kk) {
                bf16x8 af[4], bfr[4];
#pragma unroll
                for (int i = 0; i < 4; ++i) {
                    int row = wr + i * 16 + ln;
                    af[i]  = ld_frag(&uL.w2s.q[row][((kk * 4 + quad) ^ ((row >> 3) & 7)) * 8]);
                }
#pragma unroll
                for (int j = 0; j < 4; ++j) {
                    int row = wc + j * 16 + ln;
                    bfr[j] = ld_frag(&uL.w2s.k[row][((kk * 4 + quad) ^ ((row >> 3) & 7)) * 8]);
                }
#pragma unroll
                for (int i = 0; i < 4; ++i)
#pragma unroll
                    for (int j = 0; j < 4; ++j)
                        acc[i][j] = __builtin_amdgcn_mfma_f32_16x16x32_bf16(af[i], bfr[j], acc[i][j], 0, 0, 0);
            }
        }
#pragma unroll
        for (int i = 0; i < 4; ++i)
#pragma unroll
            for (int j = 0; j < 4; ++j)
#pragma unroll
                for (int r = 0; r < 4; ++r)
                    atomicAdd(&w2f[(size_t)(m0 + wr + i * 16 + quad * 4 + r) * DIM +
                                   n0 + wc + j * 16 + ln], acc[i][j][r]);
        return;
    }

    const int v  = bx - W2_BLK;
    const int b  = v / 12;
    const int d0 = (v % 12) * 64;
    const float* src = videos + (size_t)b * NV * DIM;
#pragma unroll
    for (int p = 0; p < 8; ++p) {
        int f  = t + p * 256;
        int vv = f >> 4;
        int c4 = f & 15;
        float4 x = *(const float4*)(src + (size_t)vv * DIM + d0 + c4 * 4);
        u16x4 o = { f2bf(x.x), f2bf(x.y), f2bf(x.z), f2bf(x.w) };
        uL.T[c4 * 4 + 0][vv] = o[0];
        uL.T[c4 * 4 + 1][vv] = o[1];
        uL.T[c4 * 4 + 2][vv] = o[2];
        uL.T[c4 * 4 + 3][vv] = o[3];
        *(u16x4*)(vbf + ((size_t)b * NV + vv) * DIM + d0 + c4 * 4) = o;
    }
    __syncthreads();
#pragma unroll
    for (int p = 0; p < 4; ++p) {
        int f  = t + p * 256;
        int dl = f >> 4;
        int v8 = f & 15;
        int d  = d0 + dl;
        int it = d >> 7, wv = (d >> 4) & 7, lnn = d & 15;
        int ks = v8 >> 2, qd = v8 & 3;
        int lane = qd * 16 + lnn;
        size_t off = ((((size_t)b * 6 + it) * 8 + wv) * 4 + ks) * 512 + lane * 8;
        *(u16x8*)(vt2 + off) = *(const u16x8*)&uL.T[dl][v8 * 8];
    }
}

__global__ __launch_bounds__(512) void g_kernel(const u16* __restrict__ A,
                                                const float* __restrict__ Wf,
                                                u16* __restrict__ C) {
    __shared__ u16 sA[128][64];
    __shared__ u16 sB[128][72];
    const int t    = threadIdx.x;
    const int w    = t >> 6;
    const int lane = t & 63;
    const int quad = lane >> 4;
    const int ln   = lane & 15;

    int m0, n0;
    {
        int i = blockIdx.x;
        int xcd = i & 7, s = i >> 3;
        m0 = ((s / 6) * 8 + xcd) * 128;
        n0 = (s % 6) * 128;
    }

    const int wr = (w >> 2) * 64;
    const int wc = (w & 3) * 32;
    const int srow   = lane >> 3;
    const int schunk = (lane & 7) ^ srow;

    f32x4 acc[4][2] = {};
#pragma unroll
    for (int ks = 0; ks < 12; ++ks) {
        __syncthreads();
#pragma unroll
        for (int p = 0; p < 2; ++p) {
            int rb = w * 16 + p * 8;
            gld16(A + (size_t)(m0 + rb + srow) * DIM + ks * 64 + schunk * 8, &sA[rb][0]);
        }
#pragma unroll
        for (int p = 0; p < 4; ++p) {
            int idx = t + p * 512;
            int row = idx >> 4, c4 = idx & 15;
            float4 x = *(const float4*)(Wf + (size_t)(n0 + row) * DIM + ks * 64 + c4 * 4);
            u16x4 o = { f2bf(x.x), f2bf(x.y), f2bf(x.z), f2bf(x.w) };
            int swz = ((c4 >> 1) ^ (row & 7)) * 8 + (c4 & 1) * 4;
            *(u16x4*)&sB[row][swz] = o;
        }
        __syncthreads();
#pragma unroll
        for (int kk = 0; kk < 2; ++kk) {
            bf16x8 af[4], bfr[2];
#pragma unroll
            for (int i = 0; i < 4; ++i)
                af[i]  = ld_frag(&sA[wr + i * 16 + ln][((kk * 4 + quad) ^ (ln & 7)) * 8]);
#pragma unroll
            for (int j = 0; j < 2; ++j)
                bfr[j] = ld_frag(&sB[wc + j * 16 + ln][((kk * 4 + quad) ^ (ln & 7)) * 8]);
#pragma unroll
            for (int i = 0; i < 4; ++i)
#pragma unroll
                for (int j = 0; j < 2; ++j)
                    acc[i][j] = __builtin_amdgcn_mfma_f32_16x16x32_bf16(af[i], bfr[j], acc[i][j], 0, 0, 0);
        }
    }
#pragma unroll
    for (int i = 0; i < 4; ++i)
#pragma unroll
        for (int j = 0; j < 2; ++j)
#pragma unroll
            for (int r = 0; r < 4; ++r)
                C[(size_t)(m0 + wr + i * 16 + quad * 4 + r) * DIM + n0 + wc + j * 16 + ln] =
                    f2bf(acc[i][j][r]);
}

__global__ __launch_bounds__(512) void attn_kernel(const float* __restrict__ Qf,
                                                   const u16* __restrict__ K,
                                                   const u16* __restrict__ Vt2,
                                                   const int* __restrict__ mask,
                                                   float* __restrict__ out) {
    int b, l0;
    {
        int i = blockIdx.x;
        int xcd = i & 7, s = i >> 3;
        b  = (s >> 3) * 8 + xcd;
        l0 = (s & 7) * 64;
    }
    const int t    = threadIdx.x;
    const int w    = t >> 6;
    const int lane = t & 63;
    const int quad = lane >> 4;
    const int ln   = lane & 15;

    __shared__ union {
        struct { u16 q[2][64][64]; u16 k[2][128][64]; } st;
        float s[64][132];
    } uA;
    __shared__ u16 sP[64][136];
    __shared__ float sBias[128];

    const float* Qb = Qf + ((size_t)b * LQ + l0) * DIM;
    const u16*   Kb = K + (size_t)b * NV * DIM;
    if (t < NV) sBias[t] = mask[b * NV + t] ? 0.0f : -1e9f;

    const int srow   = lane >> 3;
    const int schunk = (lane & 7) ^ srow;
    const int qrow = t >> 3;
    const int qc8  = t & 7;
    const int qswz = (qc8 ^ (qrow & 7)) * 8;

    auto stageK = [&](int ks, int sel) {
        gld16(Kb + (size_t)(w * 16 + srow) * DIM + ks * 64 + schunk * 8, &uA.st.k[sel][w * 16][0]);
        gld16(Kb + (size_t)(w * 16 + 8 + srow) * DIM + ks * 64 + schunk * 8, &uA.st.k[sel][w * 16 + 8][0]);
    };
    auto loadQ = [&](int ks, float4& x0, float4& x1) {
        const float* p = Qb + (size_t)qrow * DIM + ks * 64 + qc8 * 8;
        x0 = *(const float4*)p;
        x1 = *(const float4*)(p + 4);
    };
    auto writeQ = [&](int sel, const float4& x0, const float4& x1) {
        u16x8 o = { f2bf(x0.x), f2bf(x0.y), f2bf(x0.z), f2bf(x0.w),
                    f2bf(x1.x), f2bf(x1.y), f2bf(x1.z), f2bf(x1.w) };
        *(u16x8*)&uA.st.q[sel][qrow][qswz] = o;
    };

    f32x4 accS[4] = {};
    {
        float4 x0, x1;
        loadQ(0, x0, x1);
        stageK(0, 0);
        writeQ(0, x0, x1);
    }
#pragma unroll
    for (int ks = 0; ks < 12; ++ks) {
        __syncthreads();
        const int sel = ks & 1;
        float4 nx0, nx1;
        if (ks < 11) {
            loadQ(ks + 1, nx0, nx1);
            stageK(ks + 1, sel ^ 1);
        }
#pragma unroll
        for (int kk = 0; kk < 2; ++kk) {
            bf16x8 bfr = ld_frag(&uA.st.k[sel][w * 16 + ln][((kk * 4 + quad) ^ (ln & 7)) * 8]);
#pragma unroll
            for (int i = 0; i < 4; ++i) {
                bf16x8 af = ld_frag(&uA.st.q[sel][i * 16 + ln][((kk * 4 + quad) ^ (ln & 7)) * 8]);
                accS[i] = __builtin_amdgcn_mfma_f32_16x16x32_bf16(af, bfr, accS[i], 0, 0, 0);
            }
        }
        if (ks < 11) writeQ(sel ^ 1, nx0, nx1);
    }
    __syncthreads();
    const float scale = 0.03608439182435161f;
#pragma unroll
    for (int i = 0; i < 4; ++i)
#pragma unroll
        for (int r = 0; r < 4; ++r)
            uA.s[i * 16 + quad * 4 + r][w * 16 + ln] = accS[i][r] * scale;
    __syncthreads();

    {
        const int row = t >> 3, seg = t & 7;
        float vals[16];
        float mx = -3.0e38f;
#pragma unroll
        for (int c = 0; c < 4; ++c) {
            float4 x  = *(const float4*)&uA.s[row][seg * 16 + c * 4];
            float4 bz = *(const float4*)&sBias[seg * 16 + c * 4];
            float a0 = x.x + bz.x, a1 = x.y + bz.y, a2 = x.z + bz.z, a3 = x.w + bz.w;
            vals[c * 4 + 0] = a0; vals[c * 4 + 1] = a1;
            vals[c * 4 + 2] = a2; vals[c * 4 + 3] = a3;
            mx = fmaxf(mx, fmaxf(fmaxf(a0, a1), fmaxf(a2, a3)));
        }
        mx = fmaxf(mx, __shfl_xor(mx, 1));
        mx = fmaxf(mx, __shfl_xor(mx, 2));
        mx = fmaxf(mx, __shfl_xor(mx, 4));
        float sum = 0.0f;
#pragma unroll
        for (int c = 0; c < 16; ++c) { float e = __expf(vals[c] - mx); vals[c] = e; sum += e; }
        sum += __shfl_xor(sum, 1);
        sum += __shfl_xor(sum, 2);
        sum += __shfl_xor(sum, 4);
        const float inv = 1.0f / sum;
#pragma unroll
        for (int h = 0; h < 2; ++h) {
            u16x8 pk;
#pragma unroll
            for (int e = 0; e < 8; ++e) pk[e] = f2bf(vals[h * 8 + e] * inv);
            *(u16x8*)&sP[row][seg * 16 + h * 8] = pk;
        }
    }
    __syncthreads();

    bf16x8 paf[4][4];
#pragma unroll
    for (int i = 0; i < 4; ++i)
#pragma unroll
        for (int ks = 0; ks < 4; ++ks)
            paf[i][ks] = ld_frag(&sP[i * 16 + ln][ks * 32 + quad * 8]);

    const u16* V2 = Vt2 + (size_t)b * 6 * 8 * 4 * 512;
    float*     Ob = out + ((size_t)b * LQ + l0) * DIM;
    for (int it = 0; it < 6; ++it) {
        f32x4 accO[4] = {};
#pragma unroll
        for (int ks = 0; ks < 4; ++ks) {
            bf16x8 bv = ld_frag(V2 + (((size_t)(it * 8 + w)) * 4 + ks) * 512 + lane * 8);
#pragma unroll
            for (int i = 0; i < 4; ++i)
                accO[i] = __builtin_amdgcn_mfma_f32_16x16x32_bf16(paf[i][ks], bv, accO[i], 0, 0, 0);
        }
#pragma unroll
        for (int i = 0; i < 4; ++i)
#pragma unroll
            for (int r = 0; r < 4; ++r)
                Ob[(size_t)(i * 16 + quad * 4 + r) * DIM + it * 128 + w * 16 + ln] = accO[i][r];
    }
}

// ---------------------------------------------------------------------------
extern "C" void kernel_launch(void* const* d_in, const int* in_sizes, int n_in,
                              void* d_out, int out_size, void* d_ws, size_t ws_size,
                              hipStream_t stream) {
    const float* lines  = (const float*)d_in[0];
    const float* videos = (const float*)d_in[1];
    const int*   mask   = (const int*)d_in[2];
    const float* w_q    = (const float*)d_in[3];
    const float* w_k    = (const float*)d_in[4];
    float*       out    = (float*)d_out;

    u16*   gw  = (u16*)d_ws;                      // G: 4096x768 bf16 (6.3 MB)
    u16*   vt2 = gw  + (size_t)NB * NV * DIM;     // 32x768x128 (frag order)
    u16*   vbf = vt2 + (size_t)NB * DIM * NV;     // videos bf16 (6.3 MB)
    float* w2f = (float*)(vbf + (size_t)NB * NV * DIM);  // M fp32 (2.25 MB)

    void* args[] = { (void*)&lines, (void*)&videos, (void*)&mask, (void*)&w_q,
                     (void*)&w_k, (void*)&out, (void*)&gw, (void*)&vt2,
                     (void*)&vbf, (void*)&w2f };
    hipError_t err = hipLaunchCooperativeKernel((void*)fused_kernel, dim3(256), dim3(512),
                                                args, 0, stream);
    if (err != hipSuccess) {
        // Fallback: proven 4-dispatch path.
        hipMemsetAsync(w2f, 0, (size_t)DIM * DIM * sizeof(float), stream);
        prep_kernel<<<W2_BLK + 384, 256, 0, stream>>>(w_q, w_k, videos, w2f, vt2, vbf);
        g_kernel   <<<192, 512, 0, stream>>>(vbf, w2f, gw);
        attn_kernel<<<256, 512, 0, stream>>>(lines, gw, vt2, mask, out);
    }
}

// Round 7
// 217.769 us; speedup vs baseline: 1.1393x; 1.1393x over previous
//
#include <hip/hip_runtime.h>

#define DIM 768
#define NB  32
#define LQ  512
#define NV  128
#define W2SZ 589824          // DIM*DIM

typedef unsigned short u16;
typedef unsigned int   u32;
typedef __bf16 bf16x8 __attribute__((ext_vector_type(8)));
typedef float  f32x4  __attribute__((ext_vector_type(4)));
typedef u16    u16x8  __attribute__((ext_vector_type(8)));
typedef u16    u16x4  __attribute__((ext_vector_type(4)));

typedef __attribute__((address_space(1))) const void gvoid;
typedef __attribute__((address_space(3))) void       svoid;

__device__ __forceinline__ u16 f2bf(float f) {
    u32 u = __float_as_uint(f);
    return (u16)((u + 0x7FFFu + ((u >> 16) & 1u)) >> 16);   // RNE
}

__device__ __forceinline__ bf16x8 ld_frag(const u16* p) {
    return __builtin_bit_cast(bf16x8, *(const u16x8*)p);
}

__device__ __forceinline__ void gld16(const void* g, void* l) {
    __builtin_amdgcn_global_load_lds((gvoid*)g, (svoid*)l, 16, 0, 0);
}

// flag layout (ints): fw2[6] @0, fvb[32] @8, fvt[32] @40, fk[32] @72
#define FW2 0
#define FVB 8
#define FVT 40
#define FK  72

// Bounded spin: identical behavior when sync works (waits are <100us);
// converts any unforeseen deadlock into a visible wrong-answer instead of
// a harness hang. Cap ~= 2^20 iters * ~128cy = ~56ms @2.4GHz.
__device__ __forceinline__ void wait_ge(int* p, int n) {
    int iters = 0;
    while (__hip_atomic_load(p, __ATOMIC_RELAXED, __HIP_MEMORY_SCOPE_AGENT) < n) {
        __builtin_amdgcn_s_sleep(2);
        if (++iters > (1 << 20)) break;
    }
    (void)__hip_atomic_load(p, __ATOMIC_ACQUIRE, __HIP_MEMORY_SCOPE_AGENT);  // buffer_inv once
}

// ===========================================================================
// Single dataflow kernel, 256 blocks x 512 threads, flag-synced phases:
//   blocks [0,144):   W2 partial (tile 36 x ksplit 4) -> w2p[kc], sig fw2
//   blocks [144,240): videos -> vt2 + vbf (4 quarter-units each), sig fvb/fvt
//   blocks [0,192):   g tile: wait fw2(panel)=24 & fvb(b)=12, sig fk[b]
//   all 256:          attn: wait fk[b]=6 & fvt[b]=12, write out
// W2 wave decomposition: 8 waves as 4x2 of 32x64 (wr=(w>>1)*32, wc=(w&1)*64)
// -- the exact layout verified in the round-3 cooperative run. (The previous
// round's 4-wave layout under 8 waves wrote OOB into the flags array.)
// Residency: LDS 65.5KB -> <=2 blocks/CU; grid 256 = #CUs -> all co-resident.
// ===========================================================================
__global__ __launch_bounds__(512, 2) void mega_kernel(const float* __restrict__ lines,
                                                      const float* __restrict__ videos,
                                                      const int*   __restrict__ mask,
                                                      const float* __restrict__ w_q,
                                                      const float* __restrict__ w_k,
                                                      float* __restrict__ out,
                                                      u16* __restrict__ gw,
                                                      u16* __restrict__ vt2,
                                                      u16* __restrict__ vbf,
                                                      float* __restrict__ w2f,
                                                      int* __restrict__ flags) {
    __shared__ union {
        struct { u16 q[128][72]; u16 k[128][72]; } w2s;        // W2: 36 KB
        u16 T[2][64][136];                                     // videos: 34.8 KB
        struct { u16 A[128][64]; u16 B[128][72]; } gs;         // g: 34 KB
        struct {
            union {
                struct { u16 q[2][64][64]; u16 k[2][128][64]; } st;  // 48 KB
                float s[64][132];
            } u;
            u16 p[64][136];
            float bias[128];
        } at;                                                  // attn: 65.5 KB
    } sm;

    const int bx   = blockIdx.x;
    const int t    = threadIdx.x;
    const int w    = t >> 6;
    const int lane = t & 63;
    const int quad = lane >> 4;
    const int ln   = lane & 15;

    // ================= Phase A =================
    if (bx < 144) {
        // ---- W2 partial: w2p[kc][m][n] = sum_{e in 192-chunk} wq[e][m]*wk[e][n] ----
        const int tile = bx >> 2, kc = bx & 3;
        const int m0 = (tile / 6) * 128;
        const int n0 = (tile % 6) * 128;
        const int wr = (w >> 1) * 32;                   // 8 waves: 4x2 of 32x64
        const int wc = (w & 1) * 64;
        f32x4 acc[2][4] = {};
        for (int ks = kc * 3; ks < kc * 3 + 3; ++ks) {
            __syncthreads();
            const int e0 = ks * 64;
#pragma unroll
            for (int p = 0; p < 4; ++p) {               // 64 e-rows x 32 d-float4
                int f  = t + p * 512;
                int r  = f >> 5;
                int c4 = f & 31;
                float4 xq = *(const float4*)(w_q + (size_t)(e0 + r) * DIM + m0 + c4 * 4);
                float4 xk = *(const float4*)(w_k + (size_t)(e0 + r) * DIM + n0 + c4 * 4);
                int swz = ((r >> 3) ^ ((c4 >> 1) & 7)) * 8 + (r & 7);
                sm.w2s.q[c4 * 4 + 0][swz] = f2bf(xq.x);
                sm.w2s.q[c4 * 4 + 1][swz] = f2bf(xq.y);
                sm.w2s.q[c4 * 4 + 2][swz] = f2bf(xq.z);
                sm.w2s.q[c4 * 4 + 3][swz] = f2bf(xq.w);
                sm.w2s.k[c4 * 4 + 0][swz] = f2bf(xk.x);
                sm.w2s.k[c4 * 4 + 1][swz] = f2bf(xk.y);
                sm.w2s.k[c4 * 4 + 2][swz] = f2bf(xk.z);
                sm.w2s.k[c4 * 4 + 3][swz] = f2bf(xk.w);
            }
            __syncthreads();
#pragma unroll
            for (int kk = 0; kk < 2; ++kk) {
                bf16x8 af[2], bfr[4];
#pragma unroll
                for (int i = 0; i < 2; ++i) {
                    int row = wr + i * 16 + ln;
                    af[i]  = ld_frag(&sm.w2s.q[row][((kk * 4 + quad) ^ ((row >> 3) & 7)) * 8]);
                }
#pragma unroll
                for (int j = 0; j < 4; ++j) {
                    int row = wc + j * 16 + ln;
                    bfr[j] = ld_frag(&sm.w2s.k[row][((kk * 4 + quad) ^ ((row >> 3) & 7)) * 8]);
                }
#pragma unroll
                for (int i = 0; i < 2; ++i)
#pragma unroll
                    for (int j = 0; j < 4; ++j)
                        acc[i][j] = __builtin_amdgcn_mfma_f32_16x16x32_bf16(af[i], bfr[j], acc[i][j], 0, 0, 0);
            }
        }
        float* wp = w2f + (size_t)kc * W2SZ;
#pragma unroll
        for (int i = 0; i < 2; ++i)
#pragma unroll
            for (int j = 0; j < 4; ++j)
#pragma unroll
                for (int r = 0; r < 4; ++r)
                    wp[(size_t)(m0 + wr + i * 16 + quad * 4 + r) * DIM +
                       n0 + wc + j * 16 + ln] = acc[i][j][r];
        __syncthreads();
        if (t == 0) { __threadfence(); atomicAdd(&flags[FW2 + tile / 6], 1); }
    } else if (bx < 240) {
        // ---- videos -> vt2 + vbf: 4 quarter-units per block, 2 passes x 2 halves ----
        const int half = t >> 8;
        const int tl   = t & 255;
        for (int pass = 0; pass < 2; ++pass) {
            const int v  = (bx - 144) * 4 + pass * 2 + half;    // [0,384)
            const int b  = v / 12;
            const int d0 = (v % 12) * 64;
            const float* src = videos + (size_t)b * NV * DIM;
            if (pass) __syncthreads();                          // protect T reuse
#pragma unroll
            for (int p = 0; p < 8; ++p) {
                int f  = tl + p * 256;
                int vv = f >> 4;
                int c4 = f & 15;
                float4 x = *(const float4*)(src + (size_t)vv * DIM + d0 + c4 * 4);
                u16x4 o = { f2bf(x.x), f2bf(x.y), f2bf(x.z), f2bf(x.w) };
                sm.T[half][c4 * 4 + 0][vv] = o[0];
                sm.T[half][c4 * 4 + 1][vv] = o[1];
                sm.T[half][c4 * 4 + 2][vv] = o[2];
                sm.T[half][c4 * 4 + 3][vv] = o[3];
                *(u16x4*)(vbf + ((size_t)b * NV + vv) * DIM + d0 + c4 * 4) = o;
            }
            __syncthreads();
#pragma unroll
            for (int p = 0; p < 4; ++p) {
                int f  = tl + p * 256;
                int dl = f >> 4;
                int v8 = f & 15;                                // = ks*4 + quad
                int d  = d0 + dl;
                int it = d >> 7, wv = (d >> 4) & 7, lnn = d & 15;
                int ksv = v8 >> 2, qd = v8 & 3;
                int lane2 = qd * 16 + lnn;
                size_t off = ((((size_t)b * 6 + it) * 8 + wv) * 4 + ksv) * 512 + lane2 * 8;
                *(u16x8*)(vt2 + off) = *(const u16x8*)&sm.T[half][dl][v8 * 8];
            }
            __syncthreads();
            if (tl == 0) {
                __threadfence();
                atomicAdd(&flags[FVB + b], 1);
                atomicAdd(&flags[FVT + b], 1);
            }
        }
    }

    // ================= Phase B: G = vbf @ W2^T (192 blocks) =================
    if (bx < 192) {
        int m0, n0;
        {
            int i = bx;
            int xcd = i & 7, s = i >> 3;
            m0 = ((s / 6) * 8 + xcd) * 128;
            n0 = (s % 6) * 128;
        }
        const int gb = m0 >> 7;                         // batch of this m-panel
        if (t == 0) {
            wait_ge(&flags[FW2 + (n0 >> 7)], 24);
            wait_ge(&flags[FVB + gb], 12);
        }
        __syncthreads();

        const int wr = (w >> 2) * 64;
        const int wc = (w & 3) * 32;
        const int srow   = lane >> 3;
        const int schunk = (lane & 7) ^ srow;

        f32x4 acc[4][2] = {};
#pragma unroll
        for (int ks = 0; ks < 12; ++ks) {
            __syncthreads();
#pragma unroll
            for (int p = 0; p < 2; ++p) {               // A: 128 rows via gld16
                int rb = w * 16 + p * 8;
                gld16(vbf + (size_t)(m0 + rb + srow) * DIM + ks * 64 + schunk * 8, &sm.gs.A[rb][0]);
            }
#pragma unroll
            for (int p = 0; p < 4; ++p) {               // B: sum 4 fp32 partials, convert
                int idx = t + p * 512;
                int row = idx >> 4, c4 = idx & 15;
                const float* bp = w2f + (size_t)(n0 + row) * DIM + ks * 64 + c4 * 4;
                float4 x0 = *(const float4*)bp;
                float4 x1 = *(const float4*)(bp + W2SZ);
                float4 x2 = *(const float4*)(bp + 2 * W2SZ);
                float4 x3 = *(const float4*)(bp + 3 * W2SZ);
                float sx = x0.x + x1.x + x2.x + x3.x;
                float sy = x0.y + x1.y + x2.y + x3.y;
                float sz = x0.z + x1.z + x2.z + x3.z;
                float sw = x0.w + x1.w + x2.w + x3.w;
                u16x4 o = { f2bf(sx), f2bf(sy), f2bf(sz), f2bf(sw) };
                int swz = ((c4 >> 1) ^ (row & 7)) * 8 + (c4 & 1) * 4;
                *(u16x4*)&sm.gs.B[row][swz] = o;
            }
            __syncthreads();
#pragma unroll
            for (int kk = 0; kk < 2; ++kk) {
                bf16x8 af[4], bfr[2];
#pragma unroll
                for (int i = 0; i < 4; ++i)
                    af[i]  = ld_frag(&sm.gs.A[wr + i * 16 + ln][((kk * 4 + quad) ^ (ln & 7)) * 8]);
#pragma unroll
                for (int j = 0; j < 2; ++j)
                    bfr[j] = ld_frag(&sm.gs.B[wc + j * 16 + ln][((kk * 4 + quad) ^ (ln & 7)) * 8]);
#pragma unroll
                for (int i = 0; i < 4; ++i)
#pragma unroll
                    for (int j = 0; j < 2; ++j)
                        acc[i][j] = __builtin_amdgcn_mfma_f32_16x16x32_bf16(af[i], bfr[j], acc[i][j], 0, 0, 0);
            }
        }
#pragma unroll
        for (int i = 0; i < 4; ++i)
#pragma unroll
            for (int j = 0; j < 2; ++j)
#pragma unroll
                for (int r = 0; r < 4; ++r)
                    gw[(size_t)(m0 + wr + i * 16 + quad * 4 + r) * DIM + n0 + wc + j * 16 + ln] =
                        f2bf(acc[i][j][r]);
        __syncthreads();
        if (t == 0) { __threadfence(); atomicAdd(&flags[FK + gb], 1); }
    }

    // ================= Phase C: attention (all 256 blocks) =================
    {
        int b, l0;
        {
            int i = bx;
            int xcd = i & 7, s = i >> 3;
            b  = (s >> 3) * 8 + xcd;
            l0 = (s & 7) * 64;
        }
        if (t == 0) {
            wait_ge(&flags[FK + b], 6);
            wait_ge(&flags[FVT + b], 12);
        }
        __syncthreads();

        const float* Qb = lines + ((size_t)b * LQ + l0) * DIM;
        const u16*   Kb = gw + (size_t)b * NV * DIM;
        if (t < NV) sm.at.bias[t] = mask[b * NV + t] ? 0.0f : -1e9f;

        const int srow   = lane >> 3;
        const int schunk = (lane & 7) ^ srow;
        const int qrow = t >> 3;
        const int qc8  = t & 7;
        const int qswz = (qc8 ^ (qrow & 7)) * 8;

        auto stageK = [&](int ks, int sel) {
            gld16(Kb + (size_t)(w * 16 + srow) * DIM + ks * 64 + schunk * 8, &sm.at.u.st.k[sel][w * 16][0]);
            gld16(Kb + (size_t)(w * 16 + 8 + srow) * DIM + ks * 64 + schunk * 8, &sm.at.u.st.k[sel][w * 16 + 8][0]);
        };
        auto loadQ = [&](int ks, float4& x0, float4& x1) {
            const float* p = Qb + (size_t)qrow * DIM + ks * 64 + qc8 * 8;
            x0 = *(const float4*)p;
            x1 = *(const float4*)(p + 4);
        };
        auto writeQ = [&](int sel, const float4& x0, const float4& x1) {
            u16x8 o = { f2bf(x0.x), f2bf(x0.y), f2bf(x0.z), f2bf(x0.w),
                        f2bf(x1.x), f2bf(x1.y), f2bf(x1.z), f2bf(x1.w) };
            *(u16x8*)&sm.at.u.st.q[sel][qrow][qswz] = o;
        };

        // ---- S = Q K^T ----
        f32x4 accS[4] = {};
        {
            float4 x0, x1;
            loadQ(0, x0, x1);
            stageK(0, 0);
            writeQ(0, x0, x1);
        }
#pragma unroll
        for (int ks = 0; ks < 12; ++ks) {
            __syncthreads();
            const int sel = ks & 1;
            float4 nx0, nx1;
            if (ks < 11) {
                loadQ(ks + 1, nx0, nx1);
                stageK(ks + 1, sel ^ 1);
            }
#pragma unroll
            for (int kk = 0; kk < 2; ++kk) {
                bf16x8 bfr = ld_frag(&sm.at.u.st.k[sel][w * 16 + ln][((kk * 4 + quad) ^ (ln & 7)) * 8]);
#pragma unroll
                for (int i = 0; i < 4; ++i) {
                    bf16x8 af = ld_frag(&sm.at.u.st.q[sel][i * 16 + ln][((kk * 4 + quad) ^ (ln & 7)) * 8]);
                    accS[i] = __builtin_amdgcn_mfma_f32_16x16x32_bf16(af, bfr, accS[i], 0, 0, 0);
                }
            }
            if (ks < 11) writeQ(sel ^ 1, nx0, nx1);
        }
        __syncthreads();
        const float scale = 0.03608439182435161f;       // 768^-0.5
#pragma unroll
        for (int i = 0; i < 4; ++i)
#pragma unroll
            for (int r = 0; r < 4; ++r)
                sm.at.u.s[i * 16 + quad * 4 + r][w * 16 + ln] = accS[i][r] * scale;
        __syncthreads();

        // ---- masked softmax ----
        {
            const int row = t >> 3, seg = t & 7;
            float vals[16];
            float mx = -3.0e38f;
#pragma unroll
            for (int c = 0; c < 4; ++c) {
                float4 x  = *(const float4*)&sm.at.u.s[row][seg * 16 + c * 4];
                float4 bz = *(const float4*)&sm.at.bias[seg * 16 + c * 4];
                float a0 = x.x + bz.x, a1 = x.y + bz.y, a2 = x.z + bz.z, a3 = x.w + bz.w;
                vals[c * 4 + 0] = a0; vals[c * 4 + 1] = a1;
                vals[c * 4 + 2] = a2; vals[c * 4 + 3] = a3;
                mx = fmaxf(mx, fmaxf(fmaxf(a0, a1), fmaxf(a2, a3)));
            }
            mx = fmaxf(mx, __shfl_xor(mx, 1));
            mx = fmaxf(mx, __shfl_xor(mx, 2));
            mx = fmaxf(mx, __shfl_xor(mx, 4));
            float sum = 0.0f;
#pragma unroll
            for (int c = 0; c < 16; ++c) { float e = __expf(vals[c] - mx); vals[c] = e; sum += e; }
            sum += __shfl_xor(sum, 1);
            sum += __shfl_xor(sum, 2);
            sum += __shfl_xor(sum, 4);
            const float inv = 1.0f / sum;
#pragma unroll
            for (int h = 0; h < 2; ++h) {
                u16x8 pk;
#pragma unroll
                for (int e = 0; e < 8; ++e) pk[e] = f2bf(vals[h * 8 + e] * inv);
                *(u16x8*)&sm.at.p[row][seg * 16 + h * 8] = pk;
            }
        }
        __syncthreads();

        bf16x8 paf[4][4];
#pragma unroll
        for (int i = 0; i < 4; ++i)
#pragma unroll
            for (int ks = 0; ks < 4; ++ks)
                paf[i][ks] = ld_frag(&sm.at.p[i * 16 + ln][ks * 32 + quad * 8]);

        // ---- out = P @ V ----
        const u16* V2 = vt2 + (size_t)b * 6 * 8 * 4 * 512;
        float*     Ob = out + ((size_t)b * LQ + l0) * DIM;
        for (int it = 0; it < 6; ++it) {
            f32x4 accO[4] = {};
#pragma unroll
            for (int ks = 0; ks < 4; ++ks) {
                bf16x8 bv = ld_frag(V2 + (((size_t)(it * 8 + w)) * 4 + ks) * 512 + lane * 8);
#pragma unroll
                for (int i = 0; i < 4; ++i)
                    accO[i] = __builtin_amdgcn_mfma_f32_16x16x32_bf16(paf[i][ks], bv, accO[i], 0, 0, 0);
            }
#pragma unroll
            for (int i = 0; i < 4; ++i)
#pragma unroll
                for (int r = 0; r < 4; ++r)
                    Ob[(size_t)(i * 16 + quad * 4 + r) * DIM + it * 128 + w * 16 + ln] = accO[i][r];
        }
    }
}

// ---------------------------------------------------------------------------
extern "C" void kernel_launch(void* const* d_in, const int* in_sizes, int n_in,
                              void* d_out, int out_size, void* d_ws, size_t ws_size,
                              hipStream_t stream) {
    const float* lines  = (const float*)d_in[0];
    const float* videos = (const float*)d_in[1];
    const int*   mask   = (const int*)d_in[2];
    const float* w_q    = (const float*)d_in[3];
    const float* w_k    = (const float*)d_in[4];
    float*       out    = (float*)d_out;

    u16*   gw  = (u16*)d_ws;                      // G: 4096x768 bf16 (6.3 MB)
    u16*   vt2 = gw  + (size_t)NB * NV * DIM;     // 32x768x128 (frag order)
    u16*   vbf = vt2 + (size_t)NB * DIM * NV;     // videos bf16 (6.3 MB)
    float* w2f = (float*)(vbf + (size_t)NB * NV * DIM);  // 4 x M fp32 partials (9.4 MB)
    int*   flg = (int*)(w2f + 4 * (size_t)W2SZ);  // 104 ints of flags

    hipMemsetAsync(flg, 0, 512, stream);
    mega_kernel<<<256, 512, 0, stream>>>(lines, videos, mask, w_q, w_k, out,
                                         gw, vt2, vbf, w2f, flg);
}